// Round 7
// baseline (1677.759 us; speedup 1.0000x reference)
//
#include <hip/hip_runtime.h>
#include <math.h>

#define B_   16
#define N_   2000
#define W_   32
#define F_   5
#define TH_  128
#define M_   (B_*N_)   // 32000
#define SH_  64
#define NPB  128       // nodes per block (512 threads, 8 waves) — proven backbone

typedef unsigned short u16;
typedef short short8 __attribute__((ext_vector_type(8)));
typedef float f32x4  __attribute__((ext_vector_type(4)));

__device__ __forceinline__ float leaky_(float x) { return x > 0.0f ? x : 0.2f * x; }
__device__ __forceinline__ float sigm_(float x) {
  return __fdividef(1.0f, 1.0f + __expf(-x));
}
__device__ __forceinline__ float tanh_(float x) {
  const float e2 = __expf(2.0f * x);
  return 1.0f - __fdividef(2.0f, e2 + 1.0f);
}

// round-to-nearest-even fp32 -> bf16 bits
__device__ __forceinline__ u16 f2bf(float f) {
  unsigned u = __float_as_uint(f);
  unsigned r = (u + 0x7FFFu + ((u >> 16) & 1u)) >> 16;
  return (u16)r;
}
// truncating fp32 -> bf16 (1 op; remainder captured exactly by the lo plane)
__device__ __forceinline__ u16 f2bf_tr(float f) {
  return (u16)(__float_as_uint(f) >> 16);
}
__device__ __forceinline__ float bf2f(u16 h) { return __uint_as_float(((unsigned)h) << 16); }

__device__ __forceinline__ f32x4 mfma3(short8 ah, short8 al, short8 bh, short8 bl, f32x4 c) {
  c = __builtin_amdgcn_mfma_f32_16x16x32_bf16(ah, bh, c, 0, 0, 0);
  c = __builtin_amdgcn_mfma_f32_16x16x32_bf16(al, bh, c, 0, 0, 0);
  c = __builtin_amdgcn_mfma_f32_16x16x32_bf16(ah, bl, c, 0, 0, 0);
  return c;
}

// LDS-only barrier: drain LDS ops, sync waves — but do NOT drain vmcnt,
// so weight prefetch loads stay in flight across the barrier.
__device__ __forceinline__ void bar_lds() {
  asm volatile("s_waitcnt lgkmcnt(0)" ::: "memory");
  __builtin_amdgcn_s_barrier();
  asm volatile("" ::: "memory");
}

#define S0_ (384*32)
#define S1_ (384*128)
#define XS_ (M_*W_*8)   // 8,192,000 elems per x plane (q==0 k-slice only)

// ---------------------------------------------------------------------------
// Prologue A: Wih0 (K padded 5->32) -> packed bf16 hi/lo fragments
// ---------------------------------------------------------------------------
__global__ void splitA_kernel(const float* __restrict__ Wih0,
                              u16* __restrict__ wih0h, u16* __restrict__ wih0l)
{
  const int i = blockIdx.x * 256 + threadIdx.x;
  if (i >= S0_) return;
  const int row = i >> 5, k = i & 31;
  const float v = (k < F_) ? Wih0[row * F_ + k] : 0.0f;
  const int g = row >> 7, unit = row & 127, wv = unit >> 4, li = unit & 15;
  const int qq = k >> 3, j = k & 7;
  const int p = ((wv * 3 + g) * 64 + qq * 16 + li) * 8 + j;
  const u16 h = f2bf(v);
  wih0h[p] = h;
  wih0l[p] = f2bf(v - bf2f(h));
}

// ---------------------------------------------------------------------------
// Prologue B: three K=128 matrices -> fragment-packed bf16 hi + bf16 lo
// ---------------------------------------------------------------------------
__global__ __launch_bounds__(256)
void splitB_kernel(const float* __restrict__ Whh0, const float* __restrict__ Wih1,
                   const float* __restrict__ Whh1,
                   u16* __restrict__ wpk, u16* __restrict__ wlo)
{
  const int w = blockIdx.x * 4 + (threadIdx.x >> 6);  // row id 0..1151
  const int lane = threadIdx.x & 63;
  const int mat = w / 384;
  const int r = w - mat * 384;
  const float* src = (mat == 0) ? Whh0 : (mat == 1) ? Wih1 : Whh1;
  const int g = r >> 7, unit = r & 127, wv = unit >> 4, li = unit & 15;

#pragma unroll
  for (int e = 0; e < 2; ++e) {
    const int k = lane * 2 + e;
    const float v = src[r * TH_ + k];
    const u16 h = f2bf(v);
    const u16 l = f2bf(v - bf2f(h));
    const int kt = k >> 5, rem = k & 31, qq = rem >> 3, j = rem & 7;
    const int p = (((wv * 3 + mat) * 4 + kt) * 3 + g) * 512 + (qq * 16 + li) * 8 + j;
    wpk[p] = h;
    wlo[p] = l;
  }
}

// ---------------------------------------------------------------------------
// Prologue X: x [M,W,F] -> packed bf16 hi/lo fragments, q==0 k-slice only.
// Layout (NPB=128): p = (((mb*W + t)*8 + nt)*16 + li)*8 + j
// ---------------------------------------------------------------------------
__global__ __launch_bounds__(256)
void splitX_kernel(const float* __restrict__ x,
                   u16* __restrict__ xh, u16* __restrict__ xl)
{
  const int tid = blockIdx.x * 256 + threadIdx.x;
  if (tid >= M_ * W_) return;
  const int li = tid & 15, nt = (tid >> 4) & 7, t = (tid >> 7) & 31, mb = tid >> 12;
  const int m = mb * NPB + nt * 16 + li;
  const float* px = x + (size_t)m * (W_ * F_) + t * F_;
  short8 vh, vl;
#pragma unroll
  for (int j = 0; j < 8; ++j) {
    const float v = (j < F_) ? px[j] : 0.0f;
    const u16 h = f2bf_tr(v);
    vh[j] = (short)h;
    vl[j] = (short)f2bf(v - bf2f(h));
  }
  *(short8*)(xh + (size_t)tid * 8) = vh;
  *(short8*)(xl + (size_t)tid * 8) = vl;
}

// phase -> packed-weight offset. Execution order per t:
// phases 0..3 = G2 (hhL1), 4..7 = G1 (ihL1), 8..11 = G0 (hhL0 of t+1)
#define POFF(P) ((P) < 4 ? 12288 + (P) * 1536 \
                         : ((P) < 8 ? 6144 + ((P) - 4) * 1536 \
                                    : ((P) - 8) * 1536))

// weight phase prefetch into ping-pong register buffers (parity-indexed)
#define WPREF(PN)                                                       \
  { const int o_ = wbase + POFF(PN) + laneo;                            \
    wbh[(PN) & 1][0] = *(const short8*)(wpk + o_);                      \
    wbh[(PN) & 1][1] = *(const short8*)(wpk + o_ + 512);                \
    wbh[(PN) & 1][2] = *(const short8*)(wpk + o_ + 1024);               \
    wbl[(PN) & 1][0] = *(const short8*)(wlo + o_);                      \
    wbl[(PN) & 1][1] = *(const short8*)(wlo + o_ + 512);                \
    wbl[(PN) & 1][2] = *(const short8*)(wlo + o_ + 1024); }

// ---------------------------------------------------------------------------
// Fused 2-layer GRU via split-bf16 MFMA + LayerNorm -> temb [M][128]
// 2 barriers/t with gates overlapped under MFMA phases.
//   Phase A (B-a): gatesL0 interleaved into hhL1 kt0 nt-loop, hhL1 kt1..3.
//   Phase B (B-b): ihL1 kt0..3; gatesL1 interleaved with ih0(t+1); hhL0(t+1).
// gates(nt) consumes acc[nt] right before the next GEMM's kt0 mfma3 re-inits
// it, so no extra accumulator registers are needed. Removing the barrier
// around gates lets other waves' MFMAs overlap a wave's gate VALU.
// ---------------------------------------------------------------------------
__global__ __launch_bounds__(512, 2)
void gru_mfma_kernel(const u16* __restrict__ xpkh, const u16* __restrict__ xpkl,
                     const u16* __restrict__ wih0h, const u16* __restrict__ wih0l,
                     const u16* __restrict__ wpk, const u16* __restrict__ wlo,
                     const float* __restrict__ bih0, const float* __restrict__ bhh0,
                     const float* __restrict__ bih1, const float* __restrict__ bhh1,
                     const float* __restrict__ ln1g, const float* __restrict__ ln1b,
                     float* __restrict__ temb)
{
  __shared__ u16 h0hi[NPB * TH_], h0lo[NPB * TH_];
  __shared__ u16 h1hi[NPB * TH_], h1lo[NPB * TH_];

  const int tid = threadIdx.x;
  const int lane = tid & 63, wv = tid >> 6, q = lane >> 4, li = lane & 15;
  const int mbase = blockIdx.x * NPB;
  const int unit = wv * 16 + li;   // each wave owns one 16-unit column tile
  const int laneo = lane * 8;
  const int wbase = wv * 18432;

  for (int i = tid; i < NPB * TH_ / 2; i += 512) {
    ((unsigned*)h0hi)[i] = 0u; ((unsigned*)h0lo)[i] = 0u;
    ((unsigned*)h1hi)[i] = 0u; ((unsigned*)h1lo)[i] = 0u;
  }

  const float BR0  = bih0[unit] + bhh0[unit];
  const float BZ0  = bih0[TH_ + unit] + bhh0[TH_ + unit];
  const float BNI0 = bih0[2 * TH_ + unit];
  const float BNH0 = bhh0[2 * TH_ + unit];
  const float BR1  = bih1[unit] + bhh1[unit];
  const float BZ1  = bih1[TH_ + unit] + bhh1[TH_ + unit];
  const float BNI1 = bih1[2 * TH_ + unit];
  const float BNH1 = bhh1[2 * TH_ + unit];
  const f32x4 z4 = {0.0f, 0.0f, 0.0f, 0.0f};
  const short8 z8 = {0, 0, 0, 0, 0, 0, 0, 0};

  // t-invariant ih0 B fragments, resident for the whole kernel (24 VGPR)
  short8 bih0h_[3], bih0l_[3];
#pragma unroll
  for (int g = 0; g < 3; ++g) {
    const int ro = (wv * 3 + g) * 512 + laneo;
    bih0h_[g] = *(const short8*)(wih0h + ro);
    bih0l_[g] = *(const short8*)(wih0l + ro);
  }

  // t/nt-invariant gate LDS swizzle bases
  int nbase[4];
#pragma unroll
  for (int r = 0; r < 4; ++r)
    nbase[r] = (q * 4 + r) * TH_ + ((((unit >> 3) ^ (q * 4 + r))) << 3) + (unit & 7);

  f32x4 aR[8], aZ[8], aNI[8], aNH[8];

  // gate bodies (consume acc[nt]; write h planes in place)
  auto GATE0 = [&](int nt) {
#pragma unroll
    for (int r = 0; r < 4; ++r) {
      const int idx = nt * 2048 + nbase[r];
      const float hold = bf2f(h0hi[idx]) + bf2f(h0lo[idx]);
      const float rr = sigm_(aR[nt][r] + BR0);
      const float zz = sigm_(aZ[nt][r] + BZ0);
      const float nn = tanh_(aNI[nt][r] + BNI0 + rr * (aNH[nt][r] + BNH0));
      const float hv = (1.0f - zz) * nn + zz * hold;
      const u16 hh = f2bf_tr(hv);
      h0hi[idx] = hh;
      h0lo[idx] = f2bf(hv - bf2f(hh));
    }
  };
  auto GATE1 = [&](int nt) {
#pragma unroll
    for (int r = 0; r < 4; ++r) {
      const int idx = nt * 2048 + nbase[r];
      const float hold = bf2f(h1hi[idx]) + bf2f(h1lo[idx]);
      const float rr = sigm_(aR[nt][r] + BR1);
      const float zz = sigm_(aZ[nt][r] + BZ1);
      const float nn = tanh_(aNI[nt][r] + BNI1 + rr * (aNH[nt][r] + BNH1));
      const float hv = (1.0f - zz) * nn + zz * hold;
      const u16 hh = f2bf_tr(hv);
      h1hi[idx] = hh;
      h1lo[idx] = f2bf(hv - bf2f(hh));
    }
  };

  // weight double-buffer (ping-pong on phase parity; all indices compile-time)
  short8 wbh[2][3];
  short8 wbl[2][3];

  // ---- prologue: ih0(t=0); hhL0(0) is a no-op (h0 = 0) so aNH = 0 ----
  {
    const u16* xbh = xpkh + ((size_t)(blockIdx.x * W_ + 0) * 8) * 128 + li * 8;
    const u16* xbl = xpkl + ((size_t)(blockIdx.x * W_ + 0) * 8) * 128 + li * 8;
#pragma unroll
    for (int nt = 0; nt < 8; ++nt) {
      short8 xh8 = z8, xl8 = z8;
      if (q == 0) {
        xh8 = *(const short8*)(xbh + nt * 128);
        xl8 = *(const short8*)(xbl + nt * 128);
      }
#pragma unroll
      for (int g = 0; g < 3; ++g) {
        const f32x4 c = mfma3(xh8, xl8, bih0h_[g], bih0l_[g], z4);
        if (g == 0) aR[nt] = c; else if (g == 1) aZ[nt] = c; else aNI[nt] = c;
      }
      aNH[nt] = z4;
    }
  }
  WPREF(0);   // prime phase 0 (G2 kt0)

  for (int t = 0; t < W_; ++t) {
    bar_lds();  // B-a: hhL0(t) h0-reads done; gatesL1(t-1) h1-writes visible

    // ---------- Phase A: hhL1 (G2, A=h1 old) with gatesL0 folded into kt0 ----
#pragma unroll
    for (int kt = 0; kt < 4; ++kt) {
      WPREF(kt + 1);
      const short8 bh0 = wbh[kt & 1][0], bh1 = wbh[kt & 1][1], bh2 = wbh[kt & 1][2];
      const short8 bl0 = wbl[kt & 1][0], bl1 = wbl[kt & 1][1], bl2 = wbl[kt & 1][2];
      const int ko = ((kt * 4 + q) ^ li) * 8;
#pragma unroll
      for (int nt = 0; nt < 8; ++nt) {
        if (kt == 0) GATE0(nt);          // consume layer0 acc[nt], write h0-new
        const int ab = (nt * 16 + li) * TH_ + ko;
        const short8 Ah = *(const short8*)(h1hi + ab);
        const short8 Al = *(const short8*)(h1lo + ab);
        aR[nt]  = mfma3(Ah, Al, bh0, bl0, (kt == 0) ? z4 : aR[nt]);
        aZ[nt]  = mfma3(Ah, Al, bh1, bl1, (kt == 0) ? z4 : aZ[nt]);
        aNH[nt] = mfma3(Ah, Al, bh2, bl2, (kt == 0) ? z4 : aNH[nt]);
      }
    }

    bar_lds();  // B-b: h0-new visible; all hhL1 h1-reads done

    // ---------- Phase B: ihL1 (G1, A=h0 new; phases 4..7) ----------
#pragma unroll
    for (int kt = 0; kt < 4; ++kt) {
      const int p = 4 + kt;
      WPREF(p + 1);
      const short8 bh0 = wbh[p & 1][0], bh1 = wbh[p & 1][1], bh2 = wbh[p & 1][2];
      const short8 bl0 = wbl[p & 1][0], bl1 = wbl[p & 1][1], bl2 = wbl[p & 1][2];
      const int ko = ((kt * 4 + q) ^ li) * 8;
#pragma unroll
      for (int nt = 0; nt < 8; ++nt) {
        const int ab = (nt * 16 + li) * TH_ + ko;
        const short8 Ah = *(const short8*)(h0hi + ab);
        const short8 Al = *(const short8*)(h0lo + ab);
        aR[nt]  = mfma3(Ah, Al, bh0, bl0, aR[nt]);
        aZ[nt]  = mfma3(Ah, Al, bh1, bl1, aZ[nt]);
        aNI[nt] = mfma3(Ah, Al, bh2, bl2, (kt == 0) ? z4 : aNI[nt]);
      }
    }

    // ---------- gatesL1(t) interleaved with ih0(t+1) ----------
    if (t < W_ - 1) {
      const u16* xbh = xpkh + ((size_t)(blockIdx.x * W_ + t + 1) * 8) * 128 + li * 8;
      const u16* xbl = xpkl + ((size_t)(blockIdx.x * W_ + t + 1) * 8) * 128 + li * 8;
#pragma unroll
      for (int nt = 0; nt < 8; ++nt) {
        short8 xh8 = z8, xl8 = z8;
        if (q == 0) {
          xh8 = *(const short8*)(xbh + nt * 128);
          xl8 = *(const short8*)(xbl + nt * 128);
        }
        GATE1(nt);                        // consume layer1 acc[nt], write h1-new
#pragma unroll
        for (int g = 0; g < 3; ++g) {
          const f32x4 c = mfma3(xh8, xl8, bih0h_[g], bih0l_[g], z4);
          if (g == 0) aR[nt] = c; else if (g == 1) aZ[nt] = c; else aNI[nt] = c;
        }
      }
      // ---------- hhL0(t+1) (G0, A=h0 new; phases 8..11) ----------
#pragma unroll
      for (int kt = 0; kt < 4; ++kt) {
        const int p = 8 + kt;
        WPREF((p + 1) % 12);   // kt==3 wraps: prefetch phase 0 for t+1
        const short8 bh0 = wbh[p & 1][0], bh1 = wbh[p & 1][1], bh2 = wbh[p & 1][2];
        const short8 bl0 = wbl[p & 1][0], bl1 = wbl[p & 1][1], bl2 = wbl[p & 1][2];
        const int ko = ((kt * 4 + q) ^ li) * 8;
#pragma unroll
        for (int nt = 0; nt < 8; ++nt) {
          const int ab = (nt * 16 + li) * TH_ + ko;
          const short8 Ah = *(const short8*)(h0hi + ab);
          const short8 Al = *(const short8*)(h0lo + ab);
          aR[nt]  = mfma3(Ah, Al, bh0, bl0, aR[nt]);
          aZ[nt]  = mfma3(Ah, Al, bh1, bl1, aZ[nt]);
          aNH[nt] = mfma3(Ah, Al, bh2, bl2, (kt == 0) ? z4 : aNH[nt]);
        }
      }
    } else {
#pragma unroll
      for (int nt = 0; nt < 8; ++nt) GATE1(nt);
    }
  }
  bar_lds();  // h1 final visible for LayerNorm (cross-wave reads below)

  // ---------- LayerNorm(h1) -> temb ----------
  const int n = tid >> 2, qq = tid & 3;
  float vr[32];
  float s = 0.0f;
#pragma unroll
  for (int g8 = 0; g8 < 4; ++g8) {
    const int k0 = qq * 32 + g8 * 8;
    const int g16 = (((k0 >> 3) ^ (n & 15))) * 8;
    const short8 hv = *(const short8*)(h1hi + n * TH_ + g16);
    const short8 lv = *(const short8*)(h1lo + n * TH_ + g16);
#pragma unroll
    for (int j = 0; j < 8; ++j) {
      const float f = bf2f((u16)hv[j]) + bf2f((u16)lv[j]);
      vr[g8 * 8 + j] = f;
      s += f;
    }
  }
  s += __shfl_xor(s, 1, 64); s += __shfl_xor(s, 2, 64);
  const float mu = s * (1.0f / TH_);
  float s2 = 0.0f;
#pragma unroll
  for (int k = 0; k < 32; ++k) { const float d = vr[k] - mu; s2 += d * d; }
  s2 += __shfl_xor(s2, 1, 64); s2 += __shfl_xor(s2, 2, 64);
  const float inv = rsqrtf(s2 * (1.0f / TH_) + 1e-5f);
  float* to = temb + (size_t)(mbase + n) * TH_ + qq * 32;
#pragma unroll
  for (int k = 0; k < 32; ++k)
    to[k] = (vr[k] - mu) * inv * ln1g[qq * 32 + k] + ln1b[qq * 32 + k];
}

// ---------------------------------------------------------------------------
// xp = temb @ gat_W -> [M][64]; a_src/a_dst -> [M][4]
// ---------------------------------------------------------------------------
__global__ __launch_bounds__(256)
void gat_xp_kernel(const float* __restrict__ temb, const float* __restrict__ gatW,
                   const float* __restrict__ attS, const float* __restrict__ attD,
                   float* __restrict__ xp, float* __restrict__ asrc, float* __restrict__ adst)
{
  __shared__ float ts[64][TH_ + 4];
  __shared__ float4 ws4[TH_][16];
  __shared__ float sa[64], sd[64];

  const int tid = threadIdx.x;
  const int mbase = blockIdx.x * 64;

  for (int i = tid; i < 64 * TH_; i += 256) {
    const int n = i >> 7, k = i & 127;
    ts[n][k] = temb[(size_t)mbase * TH_ + i];
  }
  for (int i = tid; i < TH_ * 16; i += 256)
    ((float4*)ws4)[i] = ((const float4*)gatW)[i];
  if (tid < 64) { sa[tid] = attS[tid]; sd[tid] = attD[tid]; }
  __syncthreads();

  const int nl = tid >> 2;
  const int q  = tid & 3;
  float4 acc[4];
#pragma unroll
  for (int i = 0; i < 4; ++i) acc[i] = make_float4(0.f, 0.f, 0.f, 0.f);

  for (int k = 0; k < TH_; ++k) {
    const float tv = ts[nl][k];
#pragma unroll
    for (int c0 = 0; c0 < 4; ++c0) {
      const float4 wv = ws4[k][q * 4 + c0];
      acc[c0].x += tv * wv.x; acc[c0].y += tv * wv.y;
      acc[c0].z += tv * wv.z; acc[c0].w += tv * wv.w;
    }
  }

  float as = 0.0f, ad = 0.0f;
#pragma unroll
  for (int c0 = 0; c0 < 4; ++c0) {
    const int base = q * 16 + c0 * 4;
    as += acc[c0].x * sa[base + 0] + acc[c0].y * sa[base + 1] +
          acc[c0].z * sa[base + 2] + acc[c0].w * sa[base + 3];
    ad += acc[c0].x * sd[base + 0] + acc[c0].y * sd[base + 1] +
          acc[c0].z * sd[base + 2] + acc[c0].w * sd[base + 3];
  }

  const int m = mbase + nl;
  asrc[m * 4 + q] = as;
  adst[m * 4 + q] = ad;
  float4* xpo = (float4*)&xp[(size_t)m * 64 + q * 16];
#pragma unroll
  for (int c0 = 0; c0 < 4; ++c0) xpo[c0] = acc[c0];
}

// ---------------------------------------------------------------------------
// CSR build on the BASE graph (shared by all 16 batch copies)
// ---------------------------------------------------------------------------
__global__ void hist_kernel(const int* __restrict__ ei, const int EB, int* __restrict__ cnt)
{
  const int e = blockIdx.x * 256 + threadIdx.x;
  if (e < EB) atomicAdd(&cnt[ei[EB + e]], 1);
}

__global__ void scan_kernel(const int* __restrict__ cnt, int* __restrict__ offs,
                            int* __restrict__ cursor)
{
  __shared__ int part[256];
  const int tid = threadIdx.x;
  const int c0 = tid * 8;
  int loc[8];
  int s = 0;
#pragma unroll
  for (int j = 0; j < 8; ++j) {
    const int idx = c0 + j;
    const int v = (idx < N_) ? cnt[idx] : 0;
    loc[j] = s; s += v;
  }
  part[tid] = s;
  __syncthreads();
  for (int o = 1; o < 256; o <<= 1) {
    const int v = (tid >= o) ? part[tid - o] : 0;
    __syncthreads();
    part[tid] += v;
    __syncthreads();
  }
  const int base = (tid > 0) ? part[tid - 1] : 0;
#pragma unroll
  for (int j = 0; j < 8; ++j) {
    const int idx = c0 + j;
    if (idx < N_) { offs[idx] = base + loc[j]; cursor[idx] = base + loc[j]; }
  }
  if (tid == 255) offs[N_] = part[255];
}

__global__ void fill_kernel(const int* __restrict__ ei, const int EB,
                            int* __restrict__ cursor, int* __restrict__ ssrc)
{
  const int e = blockIdx.x * 256 + threadIdx.x;
  if (e < EB) {
    const int d = ei[EB + e];
    const int p = atomicAdd(&cursor[d], 1);
    ssrc[p] = ei[e];
  }
}

// ---------------------------------------------------------------------------
// Per-node gather: softmax-weighted aggregate + LN + MLP head -> out[m]
// ---------------------------------------------------------------------------
__global__ __launch_bounds__(256)
void gather_kernel(const int* __restrict__ offs, const int* __restrict__ ssrc,
                   const float* __restrict__ asrc, const float* __restrict__ adst,
                   const float* __restrict__ xp,
                   const float* __restrict__ gatb,
                   const float* __restrict__ ln2g, const float* __restrict__ ln2b,
                   const float* __restrict__ W1, const float* __restrict__ b1,
                   const float* __restrict__ W2, const float* __restrict__ b2,
                   float* __restrict__ out)
{
  __shared__ float sW1[SH_ * 32];
  __shared__ float sb1[32], sW2[32];
  __shared__ float ssemb[4][SH_ + 1];

  const int tid = threadIdx.x;
  for (int i = tid; i < SH_ * 32; i += 256) sW1[i] = W1[i];
  if (tid < 32) { sb1[tid] = b1[tid]; sW2[tid] = W2[tid]; }
  __syncthreads();

  const int lane = tid & 63, grp = tid >> 6;
  const int m = blockIdx.x * 4 + grp;
  const int b = m / N_;
  const int n = m - b * N_;
  const int h = lane >> 4;

  const float adv = adst[m * 4 + h];
  const int o0 = offs[n], o1 = offs[n + 1];
  float accn = 0.0f, accd = 0.0f;
  for (int j = o0; j < o1; ++j) {
    const int s = ssrc[j] + b * N_;
    const float a = asrc[s * 4 + h];
    const float ex = __expf(leaky_(a + adv));
    accn += ex * xp[(size_t)s * 64 + lane];
    accd += ex;
  }
  {  // self loop
    const float a = asrc[m * 4 + h];
    const float ex = __expf(leaky_(a + adv));
    accn += ex * xp[(size_t)m * 64 + lane];
    accd += ex;
  }

  const float v = accn / accd + gatb[lane];
  float s1 = v;
#pragma unroll
  for (int o = 32; o >= 1; o >>= 1) s1 += __shfl_xor(s1, o, 64);
  const float mu = s1 * (1.0f / 64.0f);
  const float d0 = v - mu;
  float s2 = d0 * d0;
#pragma unroll
  for (int o = 32; o >= 1; o >>= 1) s2 += __shfl_xor(s2, o, 64);
  const float var = s2 * (1.0f / 64.0f);
  float sem = d0 * rsqrtf(var + 1e-5f) * ln2g[lane] + ln2b[lane];
  sem = leaky_(sem);

  ssemb[grp][lane] = sem;
  __syncthreads();

  float contrib = 0.0f;
  if (lane < 32) {
    float acc = sb1[lane];
    for (int c = 0; c < SH_; ++c) acc += ssemb[grp][c] * sW1[c * 32 + lane];
    acc = leaky_(acc);
    contrib = acc * sW2[lane];
  }
#pragma unroll
  for (int o = 32; o >= 1; o >>= 1) contrib += __shfl_xor(contrib, o, 64);
  if (lane == 0) out[m] = contrib + b2[0];
}

// ---------------------------------------------------------------------------
extern "C" void kernel_launch(void* const* d_in, const int* in_sizes, int n_in,
                              void* d_out, int out_size, void* d_ws, size_t ws_size,
                              hipStream_t stream)
{
  const float* x    = (const float*)d_in[0];
  const int*   ei   = (const int*)d_in[1];
  const float* Wih0 = (const float*)d_in[2];
  const float* Whh0 = (const float*)d_in[3];
  const float* bih0 = (const float*)d_in[4];
  const float* bhh0 = (const float*)d_in[5];
  const float* Wih1 = (const float*)d_in[6];
  const float* Whh1 = (const float*)d_in[7];
  const float* bih1 = (const float*)d_in[8];
  const float* bhh1 = (const float*)d_in[9];
  const float* ln1g = (const float*)d_in[10];
  const float* ln1b = (const float*)d_in[11];
  const float* gatW = (const float*)d_in[12];
  const float* attS = (const float*)d_in[13];
  const float* attD = (const float*)d_in[14];
  const float* gatb = (const float*)d_in[15];
  const float* ln2g = (const float*)d_in[16];
  const float* ln2b = (const float*)d_in[17];
  const float* W1   = (const float*)d_in[18];
  const float* b1   = (const float*)d_in[19];
  const float* W2   = (const float*)d_in[20];
  const float* b2   = (const float*)d_in[21];
  float* out = (float*)d_out;

  const int EB = in_sizes[1] / 2;

  // workspace layout
  float* ws = (float*)d_ws;
  float* temb = ws;                                  // M*128 f32
  float* xp   = temb + (size_t)M_ * TH_;             // M*64
  float* asrc = xp + (size_t)M_ * 64;                // M*4
  float* adst = asrc + (size_t)M_ * 4;               // M*4
  u16*   wh   = (u16*)(adst + (size_t)M_ * 4);       // 2*S0 + 6*S1 u16
  u16* wih0h = wh;
  u16* wih0l = wh + S0_;
  u16* wpk   = wh + 2 * S0_;                         // 3*S1 u16 packed hi
  u16* wlo   = wpk + 3 * S1_;                        // 3*S1 u16 packed lo
  u16* xpkh  = wlo + 3 * S1_;                        // XS_ u16 (x hi, q==0 slice)
  u16* xpkl  = xpkh + XS_;                           // XS_ u16 (x lo)
  int* cnt    = (int*)(xpkl + XS_);                  // N_
  int* offs   = cnt + N_;                            // N_+1
  int* cursor = offs + N_ + 1;                       // N_
  int* ssrc   = cursor + N_;                         // EB

  splitA_kernel<<<(S0_ + 255) / 256, 256, 0, stream>>>(Wih0, wih0h, wih0l);
  splitB_kernel<<<(3 * 384) / 4, 256, 0, stream>>>(Whh0, Wih1, Whh1, wpk, wlo);
  splitX_kernel<<<(M_ * W_) / 256, 256, 0, stream>>>(x, xpkh, xpkl);

  hipMemsetAsync(cnt, 0, N_ * sizeof(int), stream);
  hist_kernel<<<(EB + 255) / 256, 256, 0, stream>>>(ei, EB, cnt);
  scan_kernel<<<1, 256, 0, stream>>>(cnt, offs, cursor);
  fill_kernel<<<(EB + 255) / 256, 256, 0, stream>>>(ei, EB, cursor, ssrc);

  gru_mfma_kernel<<<M_ / NPB, 512, 0, stream>>>(
      xpkh, xpkl, wih0h, wih0l, wpk, wlo,
      bih0, bhh0, bih1, bhh1, ln1g, ln1b, temb);

  gat_xp_kernel<<<M_ / 64, 256, 0, stream>>>(temb, gatW, attS, attD, xp, asrc, adst);

  gather_kernel<<<M_ / 4, 256, 0, stream>>>(offs, ssrc, asrc, adst, xp,
                                            gatb, ln2g, ln2b, W1, b1, W2, b2, out);
}

// Round 8
// 1274.511 us; speedup vs baseline: 1.3164x; 1.3164x over previous
//
#include <hip/hip_runtime.h>
#include <math.h>

#define B_   16
#define N_   2000
#define W_   32
#define F_   5
#define TH_  128
#define M_   (B_*N_)   // 32000
#define SH_  64
#define NPB  128       // nodes per block (512 threads, 8 waves) — proven backbone

typedef unsigned short u16;
typedef short short8 __attribute__((ext_vector_type(8)));
typedef float f32x4  __attribute__((ext_vector_type(4)));

__device__ __forceinline__ float leaky_(float x) { return x > 0.0f ? x : 0.2f * x; }
__device__ __forceinline__ float sigm_(float x) {
  return __fdividef(1.0f, 1.0f + __expf(-x));
}
__device__ __forceinline__ float tanh_(float x) {
  const float e2 = __expf(2.0f * x);
  return 1.0f - __fdividef(2.0f, e2 + 1.0f);
}

// round-to-nearest-even fp32 -> bf16 bits
__device__ __forceinline__ u16 f2bf(float f) {
  unsigned u = __float_as_uint(f);
  unsigned r = (u + 0x7FFFu + ((u >> 16) & 1u)) >> 16;
  return (u16)r;
}
// truncating fp32 -> bf16 (1 op; remainder captured exactly by the lo plane)
__device__ __forceinline__ u16 f2bf_tr(float f) {
  return (u16)(__float_as_uint(f) >> 16);
}
__device__ __forceinline__ float bf2f(u16 h) { return __uint_as_float(((unsigned)h) << 16); }

__device__ __forceinline__ f32x4 mfma3(short8 ah, short8 al, short8 bh, short8 bl, f32x4 c) {
  c = __builtin_amdgcn_mfma_f32_16x16x32_bf16(ah, bh, c, 0, 0, 0);
  c = __builtin_amdgcn_mfma_f32_16x16x32_bf16(al, bh, c, 0, 0, 0);
  c = __builtin_amdgcn_mfma_f32_16x16x32_bf16(ah, bl, c, 0, 0, 0);
  return c;
}

// LDS-only barrier: drain LDS ops, sync waves — but do NOT drain vmcnt,
// so weight prefetch loads stay in flight across the barrier.
__device__ __forceinline__ void bar_lds() {
  asm volatile("s_waitcnt lgkmcnt(0)" ::: "memory");
  __builtin_amdgcn_s_barrier();
  asm volatile("" ::: "memory");
}

#define S0_ (384*32)
#define S1_ (384*128)
#define XS_ (M_*W_*8)   // 8,192,000 elems per x plane (q==0 k-slice only)

// ---------------------------------------------------------------------------
// Prologue A: Wih0 (K padded 5->32) -> packed bf16 hi/lo fragments
// ---------------------------------------------------------------------------
__global__ void splitA_kernel(const float* __restrict__ Wih0,
                              u16* __restrict__ wih0h, u16* __restrict__ wih0l)
{
  const int i = blockIdx.x * 256 + threadIdx.x;
  if (i >= S0_) return;
  const int row = i >> 5, k = i & 31;
  const float v = (k < F_) ? Wih0[row * F_ + k] : 0.0f;
  const int g = row >> 7, unit = row & 127, wv = unit >> 4, li = unit & 15;
  const int qq = k >> 3, j = k & 7;
  const int p = ((wv * 3 + g) * 64 + qq * 16 + li) * 8 + j;
  const u16 h = f2bf(v);
  wih0h[p] = h;
  wih0l[p] = f2bf(v - bf2f(h));
}

// ---------------------------------------------------------------------------
// Prologue B: three K=128 matrices -> fragment-packed bf16 hi + bf16 lo
// ---------------------------------------------------------------------------
__global__ __launch_bounds__(256)
void splitB_kernel(const float* __restrict__ Whh0, const float* __restrict__ Wih1,
                   const float* __restrict__ Whh1,
                   u16* __restrict__ wpk, u16* __restrict__ wlo)
{
  const int w = blockIdx.x * 4 + (threadIdx.x >> 6);  // row id 0..1151
  const int lane = threadIdx.x & 63;
  const int mat = w / 384;
  const int r = w - mat * 384;
  const float* src = (mat == 0) ? Whh0 : (mat == 1) ? Wih1 : Whh1;
  const int g = r >> 7, unit = r & 127, wv = unit >> 4, li = unit & 15;

#pragma unroll
  for (int e = 0; e < 2; ++e) {
    const int k = lane * 2 + e;
    const float v = src[r * TH_ + k];
    const u16 h = f2bf(v);
    const u16 l = f2bf(v - bf2f(h));
    const int kt = k >> 5, rem = k & 31, qq = rem >> 3, j = rem & 7;
    const int p = (((wv * 3 + mat) * 4 + kt) * 3 + g) * 512 + (qq * 16 + li) * 8 + j;
    wpk[p] = h;
    wlo[p] = l;
  }
}

// ---------------------------------------------------------------------------
// Prologue X: x [M,W,F] -> packed bf16 hi/lo fragments, q==0 k-slice only.
// Layout (NPB=128): p = (((mb*W + t)*8 + nt)*16 + li)*8 + j
// ---------------------------------------------------------------------------
__global__ __launch_bounds__(256)
void splitX_kernel(const float* __restrict__ x,
                   u16* __restrict__ xh, u16* __restrict__ xl)
{
  const int tid = blockIdx.x * 256 + threadIdx.x;
  if (tid >= M_ * W_) return;
  const int li = tid & 15, nt = (tid >> 4) & 7, t = (tid >> 7) & 31, mb = tid >> 12;
  const int m = mb * NPB + nt * 16 + li;
  const float* px = x + (size_t)m * (W_ * F_) + t * F_;
  short8 vh, vl;
#pragma unroll
  for (int j = 0; j < 8; ++j) {
    const float v = (j < F_) ? px[j] : 0.0f;
    const u16 h = f2bf_tr(v);
    vh[j] = (short)h;
    vl[j] = (short)f2bf(v - bf2f(h));
  }
  *(short8*)(xh + (size_t)tid * 8) = vh;
  *(short8*)(xl + (size_t)tid * 8) = vl;
}

// phase -> packed-weight offset. Execution order per t:
// phases 0..3 = G2 (hhL1), 4..7 = G1 (ihL1), 8..11 = G0 (hhL0 of t+1)
#define POFF(P) ((P) < 4 ? 12288 + (P) * 1536 \
                         : ((P) < 8 ? 6144 + ((P) - 4) * 1536 \
                                    : ((P) - 8) * 1536))

// weight phase prefetch into ping-pong register buffers (parity-indexed)
#define WPREF(PN)                                                       \
  { const int o_ = wbase + POFF(PN) + laneo;                            \
    wbh[(PN) & 1][0] = *(const short8*)(wpk + o_);                      \
    wbh[(PN) & 1][1] = *(const short8*)(wpk + o_ + 512);                \
    wbh[(PN) & 1][2] = *(const short8*)(wpk + o_ + 1024);               \
    wbl[(PN) & 1][0] = *(const short8*)(wlo + o_);                      \
    wbl[(PN) & 1][1] = *(const short8*)(wlo + o_ + 512);                \
    wbl[(PN) & 1][2] = *(const short8*)(wlo + o_ + 1024); }

// ---------------------------------------------------------------------------
// Fused 2-layer GRU via split-bf16 MFMA + LayerNorm -> temb [M][128]
// 2 barriers/t (R7-validated dependency structure) with gates as SEPARATE
// compact loops (R7's per-nt interleave spilled to scratch: WRITE_SIZE 2 GB).
// Per t: B-a | gatesL0, hhL1(G2) | B-b | ihL1(G1), gatesL1, ih0(t+1),
// hhL0(t+1)(G0). Gate loops share the barrier interval with 24 MFMA phases,
// so other waves' MFMAs overlap a wave's gate VALU.
// ---------------------------------------------------------------------------
__global__ __launch_bounds__(512, 2)
void gru_mfma_kernel(const u16* __restrict__ xpkh, const u16* __restrict__ xpkl,
                     const u16* __restrict__ wih0h, const u16* __restrict__ wih0l,
                     const u16* __restrict__ wpk, const u16* __restrict__ wlo,
                     const float* __restrict__ bih0, const float* __restrict__ bhh0,
                     const float* __restrict__ bih1, const float* __restrict__ bhh1,
                     const float* __restrict__ ln1g, const float* __restrict__ ln1b,
                     float* __restrict__ temb)
{
  __shared__ u16 h0hi[NPB * TH_], h0lo[NPB * TH_];
  __shared__ u16 h1hi[NPB * TH_], h1lo[NPB * TH_];

  const int tid = threadIdx.x;
  const int lane = tid & 63, wv = tid >> 6, q = lane >> 4, li = lane & 15;
  const int mbase = blockIdx.x * NPB;
  const int unit = wv * 16 + li;   // each wave owns one 16-unit column tile
  const int laneo = lane * 8;
  const int wbase = wv * 18432;

  for (int i = tid; i < NPB * TH_ / 2; i += 512) {
    ((unsigned*)h0hi)[i] = 0u; ((unsigned*)h0lo)[i] = 0u;
    ((unsigned*)h1hi)[i] = 0u; ((unsigned*)h1lo)[i] = 0u;
  }

  const float BR0  = bih0[unit] + bhh0[unit];
  const float BZ0  = bih0[TH_ + unit] + bhh0[TH_ + unit];
  const float BNI0 = bih0[2 * TH_ + unit];
  const float BNH0 = bhh0[2 * TH_ + unit];
  const float BR1  = bih1[unit] + bhh1[unit];
  const float BZ1  = bih1[TH_ + unit] + bhh1[TH_ + unit];
  const float BNI1 = bih1[2 * TH_ + unit];
  const float BNH1 = bhh1[2 * TH_ + unit];
  const f32x4 z4 = {0.0f, 0.0f, 0.0f, 0.0f};
  const short8 z8 = {0, 0, 0, 0, 0, 0, 0, 0};

  // t-invariant ih0 B fragments, resident for the whole kernel (24 VGPR)
  short8 bih0h_[3], bih0l_[3];
#pragma unroll
  for (int g = 0; g < 3; ++g) {
    const int ro = (wv * 3 + g) * 512 + laneo;
    bih0h_[g] = *(const short8*)(wih0h + ro);
    bih0l_[g] = *(const short8*)(wih0l + ro);
  }

  // t/nt-invariant gate LDS swizzle bases
  int nbase[4];
#pragma unroll
  for (int r = 0; r < 4; ++r)
    nbase[r] = (q * 4 + r) * TH_ + ((((unit >> 3) ^ (q * 4 + r))) << 3) + (unit & 7);

  f32x4 aR[8], aZ[8], aNI[8], aNH[8];

  // weight double-buffer (ping-pong on phase parity; all indices compile-time)
  short8 wbh[2][3];
  short8 wbl[2][3];

  // ---- prologue: ih0(t=0); hhL0(0) is a no-op (h0 = 0) so aNH = 0 ----
  {
    const u16* xbh = xpkh + ((size_t)(blockIdx.x * W_ + 0) * 8) * 128 + li * 8;
    const u16* xbl = xpkl + ((size_t)(blockIdx.x * W_ + 0) * 8) * 128 + li * 8;
#pragma unroll
    for (int nt = 0; nt < 8; ++nt) {
      short8 xh8 = z8, xl8 = z8;
      if (q == 0) {
        xh8 = *(const short8*)(xbh + nt * 128);
        xl8 = *(const short8*)(xbl + nt * 128);
      }
#pragma unroll
      for (int g = 0; g < 3; ++g) {
        const f32x4 c = mfma3(xh8, xl8, bih0h_[g], bih0l_[g], z4);
        if (g == 0) aR[nt] = c; else if (g == 1) aZ[nt] = c; else aNI[nt] = c;
      }
      aNH[nt] = z4;
    }
  }
  WPREF(0);   // prime phase 0 (G2 kt0)

  for (int t = 0; t < W_; ++t) {
    bar_lds();  // B-a: hhL0(t) h0-reads done; gatesL1(t-1) h1-writes visible

    // ---------- gates layer0 -> h0 planes (separate loop; no spill) ----------
#pragma unroll
    for (int nt = 0; nt < 8; ++nt)
#pragma unroll
      for (int r = 0; r < 4; ++r) {
        const int idx = nt * 2048 + nbase[r];
        const float hold = bf2f(h0hi[idx]) + bf2f(h0lo[idx]);
        const float rr = sigm_(aR[nt][r] + BR0);
        const float zz = sigm_(aZ[nt][r] + BZ0);
        const float nn = tanh_(aNI[nt][r] + BNI0 + rr * (aNH[nt][r] + BNH0));
        const float hv = (1.0f - zz) * nn + zz * hold;
        const u16 hh = f2bf_tr(hv);
        h0hi[idx] = hh;
        h0lo[idx] = f2bf(hv - bf2f(hh));
      }

    // ---------- hhL1 (G2, A=h1 old; phases 0..3) ----------
#pragma unroll
    for (int kt = 0; kt < 4; ++kt) {
      WPREF(kt + 1);
      const short8 bh0 = wbh[kt & 1][0], bh1 = wbh[kt & 1][1], bh2 = wbh[kt & 1][2];
      const short8 bl0 = wbl[kt & 1][0], bl1 = wbl[kt & 1][1], bl2 = wbl[kt & 1][2];
      const int ko = ((kt * 4 + q) ^ li) * 8;
#pragma unroll
      for (int nt = 0; nt < 8; ++nt) {
        const int ab = (nt * 16 + li) * TH_ + ko;
        const short8 Ah = *(const short8*)(h1hi + ab);
        const short8 Al = *(const short8*)(h1lo + ab);
        aR[nt]  = mfma3(Ah, Al, bh0, bl0, (kt == 0) ? z4 : aR[nt]);
        aZ[nt]  = mfma3(Ah, Al, bh1, bl1, (kt == 0) ? z4 : aZ[nt]);
        aNH[nt] = mfma3(Ah, Al, bh2, bl2, (kt == 0) ? z4 : aNH[nt]);
      }
    }

    bar_lds();  // B-b: h0-new visible; all hhL1 h1-reads done

    // ---------- ihL1 (G1, A=h0 new; phases 4..7) ----------
#pragma unroll
    for (int kt = 0; kt < 4; ++kt) {
      const int p = 4 + kt;
      WPREF(p + 1);
      const short8 bh0 = wbh[p & 1][0], bh1 = wbh[p & 1][1], bh2 = wbh[p & 1][2];
      const short8 bl0 = wbl[p & 1][0], bl1 = wbl[p & 1][1], bl2 = wbl[p & 1][2];
      const int ko = ((kt * 4 + q) ^ li) * 8;
#pragma unroll
      for (int nt = 0; nt < 8; ++nt) {
        const int ab = (nt * 16 + li) * TH_ + ko;
        const short8 Ah = *(const short8*)(h0hi + ab);
        const short8 Al = *(const short8*)(h0lo + ab);
        aR[nt]  = mfma3(Ah, Al, bh0, bl0, aR[nt]);
        aZ[nt]  = mfma3(Ah, Al, bh1, bl1, aZ[nt]);
        aNI[nt] = mfma3(Ah, Al, bh2, bl2, (kt == 0) ? z4 : aNI[nt]);
      }
    }

    // ---------- gates layer1 -> h1 planes (separate loop) ----------
#pragma unroll
    for (int nt = 0; nt < 8; ++nt)
#pragma unroll
      for (int r = 0; r < 4; ++r) {
        const int idx = nt * 2048 + nbase[r];
        const float hold = bf2f(h1hi[idx]) + bf2f(h1lo[idx]);
        const float rr = sigm_(aR[nt][r] + BR1);
        const float zz = sigm_(aZ[nt][r] + BZ1);
        const float nn = tanh_(aNI[nt][r] + BNI1 + rr * (aNH[nt][r] + BNH1));
        const float hv = (1.0f - zz) * nn + zz * hold;
        const u16 hh = f2bf_tr(hv);
        h1hi[idx] = hh;
        h1lo[idx] = f2bf(hv - bf2f(hh));
      }

    if (t < W_ - 1) {
      // ---------- ih0(t+1) (x pre-packed, B resident) ----------
      const u16* xbh = xpkh + ((size_t)(blockIdx.x * W_ + t + 1) * 8) * 128 + li * 8;
      const u16* xbl = xpkl + ((size_t)(blockIdx.x * W_ + t + 1) * 8) * 128 + li * 8;
#pragma unroll
      for (int nt = 0; nt < 8; ++nt) {
        short8 xh8 = z8, xl8 = z8;
        if (q == 0) {
          xh8 = *(const short8*)(xbh + nt * 128);
          xl8 = *(const short8*)(xbl + nt * 128);
        }
#pragma unroll
        for (int g = 0; g < 3; ++g) {
          const f32x4 c = mfma3(xh8, xl8, bih0h_[g], bih0l_[g], z4);
          if (g == 0) aR[nt] = c; else if (g == 1) aZ[nt] = c; else aNI[nt] = c;
        }
      }
      // ---------- hhL0(t+1) (G0, A=h0 new; phases 8..11) ----------
#pragma unroll
      for (int kt = 0; kt < 4; ++kt) {
        const int p = 8 + kt;
        WPREF((p + 1) % 12);   // kt==3 wraps: prefetch phase 0 for t+1
        const short8 bh0 = wbh[p & 1][0], bh1 = wbh[p & 1][1], bh2 = wbh[p & 1][2];
        const short8 bl0 = wbl[p & 1][0], bl1 = wbl[p & 1][1], bl2 = wbl[p & 1][2];
        const int ko = ((kt * 4 + q) ^ li) * 8;
#pragma unroll
        for (int nt = 0; nt < 8; ++nt) {
          const int ab = (nt * 16 + li) * TH_ + ko;
          const short8 Ah = *(const short8*)(h0hi + ab);
          const short8 Al = *(const short8*)(h0lo + ab);
          aR[nt]  = mfma3(Ah, Al, bh0, bl0, aR[nt]);
          aZ[nt]  = mfma3(Ah, Al, bh1, bl1, aZ[nt]);
          aNH[nt] = mfma3(Ah, Al, bh2, bl2, (kt == 0) ? z4 : aNH[nt]);
        }
      }
    }
  }
  bar_lds();  // h1 final visible for LayerNorm (cross-wave reads below)

  // ---------- LayerNorm(h1) -> temb ----------
  const int n = tid >> 2, qq = tid & 3;
  float vr[32];
  float s = 0.0f;
#pragma unroll
  for (int g8 = 0; g8 < 4; ++g8) {
    const int k0 = qq * 32 + g8 * 8;
    const int g16 = (((k0 >> 3) ^ (n & 15))) * 8;
    const short8 hv = *(const short8*)(h1hi + n * TH_ + g16);
    const short8 lv = *(const short8*)(h1lo + n * TH_ + g16);
#pragma unroll
    for (int j = 0; j < 8; ++j) {
      const float f = bf2f((u16)hv[j]) + bf2f((u16)lv[j]);
      vr[g8 * 8 + j] = f;
      s += f;
    }
  }
  s += __shfl_xor(s, 1, 64); s += __shfl_xor(s, 2, 64);
  const float mu = s * (1.0f / TH_);
  float s2 = 0.0f;
#pragma unroll
  for (int k = 0; k < 32; ++k) { const float d = vr[k] - mu; s2 += d * d; }
  s2 += __shfl_xor(s2, 1, 64); s2 += __shfl_xor(s2, 2, 64);
  const float inv = rsqrtf(s2 * (1.0f / TH_) + 1e-5f);
  float* to = temb + (size_t)(mbase + n) * TH_ + qq * 32;
#pragma unroll
  for (int k = 0; k < 32; ++k)
    to[k] = (vr[k] - mu) * inv * ln1g[qq * 32 + k] + ln1b[qq * 32 + k];
}

// ---------------------------------------------------------------------------
// xp = temb @ gat_W -> [M][64]; a_src/a_dst -> [M][4]
// ---------------------------------------------------------------------------
__global__ __launch_bounds__(256)
void gat_xp_kernel(const float* __restrict__ temb, const float* __restrict__ gatW,
                   const float* __restrict__ attS, const float* __restrict__ attD,
                   float* __restrict__ xp, float* __restrict__ asrc, float* __restrict__ adst)
{
  __shared__ float ts[64][TH_ + 4];
  __shared__ float4 ws4[TH_][16];
  __shared__ float sa[64], sd[64];

  const int tid = threadIdx.x;
  const int mbase = blockIdx.x * 64;

  for (int i = tid; i < 64 * TH_; i += 256) {
    const int n = i >> 7, k = i & 127;
    ts[n][k] = temb[(size_t)mbase * TH_ + i];
  }
  for (int i = tid; i < TH_ * 16; i += 256)
    ((float4*)ws4)[i] = ((const float4*)gatW)[i];
  if (tid < 64) { sa[tid] = attS[tid]; sd[tid] = attD[tid]; }
  __syncthreads();

  const int nl = tid >> 2;
  const int q  = tid & 3;
  float4 acc[4];
#pragma unroll
  for (int i = 0; i < 4; ++i) acc[i] = make_float4(0.f, 0.f, 0.f, 0.f);

  for (int k = 0; k < TH_; ++k) {
    const float tv = ts[nl][k];
#pragma unroll
    for (int c0 = 0; c0 < 4; ++c0) {
      const float4 wv = ws4[k][q * 4 + c0];
      acc[c0].x += tv * wv.x; acc[c0].y += tv * wv.y;
      acc[c0].z += tv * wv.z; acc[c0].w += tv * wv.w;
    }
  }

  float as = 0.0f, ad = 0.0f;
#pragma unroll
  for (int c0 = 0; c0 < 4; ++c0) {
    const int base = q * 16 + c0 * 4;
    as += acc[c0].x * sa[base + 0] + acc[c0].y * sa[base + 1] +
          acc[c0].z * sa[base + 2] + acc[c0].w * sa[base + 3];
    ad += acc[c0].x * sd[base + 0] + acc[c0].y * sd[base + 1] +
          acc[c0].z * sd[base + 2] + acc[c0].w * sd[base + 3];
  }

  const int m = mbase + nl;
  asrc[m * 4 + q] = as;
  adst[m * 4 + q] = ad;
  float4* xpo = (float4*)&xp[(size_t)m * 64 + q * 16];
#pragma unroll
  for (int c0 = 0; c0 < 4; ++c0) xpo[c0] = acc[c0];
}

// ---------------------------------------------------------------------------
// CSR build on the BASE graph (shared by all 16 batch copies)
// ---------------------------------------------------------------------------
__global__ void hist_kernel(const int* __restrict__ ei, const int EB, int* __restrict__ cnt)
{
  const int e = blockIdx.x * 256 + threadIdx.x;
  if (e < EB) atomicAdd(&cnt[ei[EB + e]], 1);
}

__global__ void scan_kernel(const int* __restrict__ cnt, int* __restrict__ offs,
                            int* __restrict__ cursor)
{
  __shared__ int part[256];
  const int tid = threadIdx.x;
  const int c0 = tid * 8;
  int loc[8];
  int s = 0;
#pragma unroll
  for (int j = 0; j < 8; ++j) {
    const int idx = c0 + j;
    const int v = (idx < N_) ? cnt[idx] : 0;
    loc[j] = s; s += v;
  }
  part[tid] = s;
  __syncthreads();
  for (int o = 1; o < 256; o <<= 1) {
    const int v = (tid >= o) ? part[tid - o] : 0;
    __syncthreads();
    part[tid] += v;
    __syncthreads();
  }
  const int base = (tid > 0) ? part[tid - 1] : 0;
#pragma unroll
  for (int j = 0; j < 8; ++j) {
    const int idx = c0 + j;
    if (idx < N_) { offs[idx] = base + loc[j]; cursor[idx] = base + loc[j]; }
  }
  if (tid == 255) offs[N_] = part[255];
}

__global__ void fill_kernel(const int* __restrict__ ei, const int EB,
                            int* __restrict__ cursor, int* __restrict__ ssrc)
{
  const int e = blockIdx.x * 256 + threadIdx.x;
  if (e < EB) {
    const int d = ei[EB + e];
    const int p = atomicAdd(&cursor[d], 1);
    ssrc[p] = ei[e];
  }
}

// ---------------------------------------------------------------------------
// Per-node gather: softmax-weighted aggregate + LN + MLP head -> out[m]
// ---------------------------------------------------------------------------
__global__ __launch_bounds__(256)
void gather_kernel(const int* __restrict__ offs, const int* __restrict__ ssrc,
                   const float* __restrict__ asrc, const float* __restrict__ adst,
                   const float* __restrict__ xp,
                   const float* __restrict__ gatb,
                   const float* __restrict__ ln2g, const float* __restrict__ ln2b,
                   const float* __restrict__ W1, const float* __restrict__ b1,
                   const float* __restrict__ W2, const float* __restrict__ b2,
                   float* __restrict__ out)
{
  __shared__ float sW1[SH_ * 32];
  __shared__ float sb1[32], sW2[32];
  __shared__ float ssemb[4][SH_ + 1];

  const int tid = threadIdx.x;
  for (int i = tid; i < SH_ * 32; i += 256) sW1[i] = W1[i];
  if (tid < 32) { sb1[tid] = b1[tid]; sW2[tid] = W2[tid]; }
  __syncthreads();

  const int lane = tid & 63, grp = tid >> 6;
  const int m = blockIdx.x * 4 + grp;
  const int b = m / N_;
  const int n = m - b * N_;
  const int h = lane >> 4;

  const float adv = adst[m * 4 + h];
  const int o0 = offs[n], o1 = offs[n + 1];
  float accn = 0.0f, accd = 0.0f;
  for (int j = o0; j < o1; ++j) {
    const int s = ssrc[j] + b * N_;
    const float a = asrc[s * 4 + h];
    const float ex = __expf(leaky_(a + adv));
    accn += ex * xp[(size_t)s * 64 + lane];
    accd += ex;
  }
  {  // self loop
    const float a = asrc[m * 4 + h];
    const float ex = __expf(leaky_(a + adv));
    accn += ex * xp[(size_t)m * 64 + lane];
    accd += ex;
  }

  const float v = accn / accd + gatb[lane];
  float s1 = v;
#pragma unroll
  for (int o = 32; o >= 1; o >>= 1) s1 += __shfl_xor(s1, o, 64);
  const float mu = s1 * (1.0f / 64.0f);
  const float d0 = v - mu;
  float s2 = d0 * d0;
#pragma unroll
  for (int o = 32; o >= 1; o >>= 1) s2 += __shfl_xor(s2, o, 64);
  const float var = s2 * (1.0f / 64.0f);
  float sem = d0 * rsqrtf(var + 1e-5f) * ln2g[lane] + ln2b[lane];
  sem = leaky_(sem);

  ssemb[grp][lane] = sem;
  __syncthreads();

  float contrib = 0.0f;
  if (lane < 32) {
    float acc = sb1[lane];
    for (int c = 0; c < SH_; ++c) acc += ssemb[grp][c] * sW1[c * 32 + lane];
    acc = leaky_(acc);
    contrib = acc * sW2[lane];
  }
#pragma unroll
  for (int o = 32; o >= 1; o >>= 1) contrib += __shfl_xor(contrib, o, 64);
  if (lane == 0) out[m] = contrib + b2[0];
}

// ---------------------------------------------------------------------------
extern "C" void kernel_launch(void* const* d_in, const int* in_sizes, int n_in,
                              void* d_out, int out_size, void* d_ws, size_t ws_size,
                              hipStream_t stream)
{
  const float* x    = (const float*)d_in[0];
  const int*   ei   = (const int*)d_in[1];
  const float* Wih0 = (const float*)d_in[2];
  const float* Whh0 = (const float*)d_in[3];
  const float* bih0 = (const float*)d_in[4];
  const float* bhh0 = (const float*)d_in[5];
  const float* Wih1 = (const float*)d_in[6];
  const float* Whh1 = (const float*)d_in[7];
  const float* bih1 = (const float*)d_in[8];
  const float* bhh1 = (const float*)d_in[9];
  const float* ln1g = (const float*)d_in[10];
  const float* ln1b = (const float*)d_in[11];
  const float* gatW = (const float*)d_in[12];
  const float* attS = (const float*)d_in[13];
  const float* attD = (const float*)d_in[14];
  const float* gatb = (const float*)d_in[15];
  const float* ln2g = (const float*)d_in[16];
  const float* ln2b = (const float*)d_in[17];
  const float* W1   = (const float*)d_in[18];
  const float* b1   = (const float*)d_in[19];
  const float* W2   = (const float*)d_in[20];
  const float* b2   = (const float*)d_in[21];
  float* out = (float*)d_out;

  const int EB = in_sizes[1] / 2;

  // workspace layout
  float* ws = (float*)d_ws;
  float* temb = ws;                                  // M*128 f32
  float* xp   = temb + (size_t)M_ * TH_;             // M*64
  float* asrc = xp + (size_t)M_ * 64;                // M*4
  float* adst = asrc + (size_t)M_ * 4;               // M*4
  u16*   wh   = (u16*)(adst + (size_t)M_ * 4);       // 2*S0 + 6*S1 u16
  u16* wih0h = wh;
  u16* wih0l = wh + S0_;
  u16* wpk   = wh + 2 * S0_;                         // 3*S1 u16 packed hi
  u16* wlo   = wpk + 3 * S1_;                        // 3*S1 u16 packed lo
  u16* xpkh  = wlo + 3 * S1_;                        // XS_ u16 (x hi, q==0 slice)
  u16* xpkl  = xpkh + XS_;                           // XS_ u16 (x lo)
  int* cnt    = (int*)(xpkl + XS_);                  // N_
  int* offs   = cnt + N_;                            // N_+1
  int* cursor = offs + N_ + 1;                       // N_
  int* ssrc   = cursor + N_;                         // EB

  splitA_kernel<<<(S0_ + 255) / 256, 256, 0, stream>>>(Wih0, wih0h, wih0l);
  splitB_kernel<<<(3 * 384) / 4, 256, 0, stream>>>(Whh0, Wih1, Whh1, wpk, wlo);
  splitX_kernel<<<(M_ * W_) / 256, 256, 0, stream>>>(x, xpkh, xpkl);

  hipMemsetAsync(cnt, 0, N_ * sizeof(int), stream);
  hist_kernel<<<(EB + 255) / 256, 256, 0, stream>>>(ei, EB, cnt);
  scan_kernel<<<1, 256, 0, stream>>>(cnt, offs, cursor);
  fill_kernel<<<(EB + 255) / 256, 256, 0, stream>>>(ei, EB, cursor, ssrc);

  gru_mfma_kernel<<<M_ / NPB, 512, 0, stream>>>(
      xpkh, xpkl, wih0h, wih0l, wpk, wlo,
      bih0, bhh0, bih1, bhh1, ln1g, ln1b, temb);

  gat_xp_kernel<<<M_ / 64, 256, 0, stream>>>(temb, gatW, attS, attD, xp, asrc, adst);

  gather_kernel<<<M_ / 4, 256, 0, stream>>>(offs, ssrc, asrc, adst, xp,
                                            gatb, ln2g, ln2b, W1, b1, W2, b2, out);
}